// Round 3
// baseline (119.263 us; speedup 1.0000x reference)
//
#include <hip/hip_runtime.h>

// Decoder: frames[m,c,k,l] = sum_n (mix[m,n,k]*mask[m,c,n,k]) * W[l,n]
// then overlap-add (hop=8) into out[m,c,t], T = (K-1)*8+16 = 128008.
// M=4 C=2 N=512 K=16000 L=16.
//
// Block = (m, 128 consecutive frames k): each lane owns TWO consecutive k's
// so every global load is float2 (512 B per wave-instruction). 4 waves each
// own 128 n's. W staged in LDS, read at wave-uniform addresses (broadcast).
// Cross-wave reduce through LDS in two c-phases; wave 0 does the overlap-add
// in-register (odd frame combines in-lane, even frame via shfl_up). Block
// boundary head/tail partials go to d_ws; boundary_kernel combines them, so
// every out element is written exactly once with '=' -> no memset, no atomics.

#define M_   4
#define C_   2
#define N_   512
#define K_   16000
#define L_   16
#define HOP  8
#define T_   ((K_ - 1) * HOP + L_)   // 128008
#define BK   128                     // frames per block (2 per lane)
#define NSEG 4                       // waves per block
#define NPW  (N_ / NSEG)             // 128
#define NB   (K_ / BK)               // 125 blocks per m
#define WS_TAIL_OFF (M_ * C_ * NB * 8)

__global__ __launch_bounds__(256, 2)
void decoder_kernel(const float* __restrict__ mix,   // [M][N][K]
                    const float* __restrict__ mask,  // [M][C][N][K]
                    const float* __restrict__ Wg,    // [L][N]
                    float* __restrict__ out,         // [M][C][T]
                    float* __restrict__ ws) {
    __shared__ float lds[8192];      // W [16][512] = 32 KB; reused for reduce

    const int tid  = threadIdx.x;
    const int lane = tid & 63;
    const int w    = tid >> 6;
    const int m    = blockIdx.x / NB;
    const int bb   = blockIdx.x % NB;
    const int k0   = bb * BK;

    for (int i = tid; i < L_ * N_; i += 256) lds[i] = Wg[i];
    __syncthreads();

    float accE[32], accO[32];        // [c*16 + l] for even/odd frame of lane
    #pragma unroll
    for (int i = 0; i < 32; ++i) { accE[i] = 0.f; accO[i] = 0.f; }

    const int n0w = w * NPW;
    const int kk  = k0 + 2 * lane;   // even frame index of this lane
    const float* pm = mix  + (size_t)m * N_ * K_ + (size_t)n0w * K_ + kk;
    const float* p0 = mask + (size_t)(m * C_) * N_ * K_ + (size_t)n0w * K_ + kk;
    const float* p1 = p0 + (size_t)N_ * K_;

    #pragma unroll 2
    for (int ch = 0; ch < NPW / 4; ++ch) {
        float2 mv[4], a0[4], a1[4];
        #pragma unroll
        for (int j = 0; j < 4; ++j) {
            mv[j] = *(const float2*)&pm[(size_t)j * K_];
            a0[j] = *(const float2*)&p0[(size_t)j * K_];
            a1[j] = *(const float2*)&p1[(size_t)j * K_];
        }
        float s0e[4], s0o[4], s1e[4], s1o[4];
        #pragma unroll
        for (int j = 0; j < 4; ++j) {
            s0e[j] = mv[j].x * a0[j].x;  s0o[j] = mv[j].y * a0[j].y;
            s1e[j] = mv[j].x * a1[j].x;  s1o[j] = mv[j].y * a1[j].y;
        }
        const int nbase = n0w + ch * 4;
        #pragma unroll
        for (int l = 0; l < L_; ++l) {
            const float4 w4 = *(const float4*)&lds[l * N_ + nbase];
            const float wv[4] = { w4.x, w4.y, w4.z, w4.w };
            #pragma unroll
            for (int j = 0; j < 4; ++j) {
                accE[l]      = fmaf(s0e[j], wv[j], accE[l]);
                accE[16 + l] = fmaf(s1e[j], wv[j], accE[16 + l]);
                accO[l]      = fmaf(s0o[j], wv[j], accO[l]);
                accO[16 + l] = fmaf(s1o[j], wv[j], accO[16 + l]);
            }
        }
        pm += (size_t)4 * K_;
        p0 += (size_t)4 * K_;
        p1 += (size_t)4 * K_;
    }

    // ---- cross-wave reduction, two c-phases (fits the 32 KB W region) ----
    #pragma unroll
    for (int c = 0; c < C_; ++c) {
        __syncthreads();
        if (w > 0) {
            float* rb = &lds[(w - 1) * 2304 + lane * 36];
            #pragma unroll
            for (int i = 0; i < 4; ++i)
                *(float4*)&rb[i * 4] = make_float4(accE[c*16+i*4], accE[c*16+i*4+1],
                                                   accE[c*16+i*4+2], accE[c*16+i*4+3]);
            #pragma unroll
            for (int i = 0; i < 4; ++i)
                *(float4*)&rb[16 + i * 4] = make_float4(accO[c*16+i*4], accO[c*16+i*4+1],
                                                        accO[c*16+i*4+2], accO[c*16+i*4+3]);
        }
        __syncthreads();
        if (w == 0) {
            #pragma unroll
            for (int r = 0; r < 3; ++r) {
                const float* rb = &lds[r * 2304 + lane * 36];
                #pragma unroll
                for (int i = 0; i < 4; ++i) {
                    const float4 v = *(const float4*)&rb[i * 4];
                    accE[c*16+i*4]   += v.x;  accE[c*16+i*4+1] += v.y;
                    accE[c*16+i*4+2] += v.z;  accE[c*16+i*4+3] += v.w;
                }
                #pragma unroll
                for (int i = 0; i < 4; ++i) {
                    const float4 v = *(const float4*)&rb[16 + i * 4];
                    accO[c*16+i*4]   += v.x;  accO[c*16+i*4+1] += v.y;
                    accO[c*16+i*4+2] += v.z;  accO[c*16+i*4+3] += v.w;
                }
            }
        }
    }

    // ---- overlap-add: t = k*8+j = frames[k][j] + frames[k-1][8+j] ----
    if (w == 0) {
        #pragma unroll
        for (int c = 0; c < C_; ++c) {
            float* ob = out + (size_t)(m * C_ + c) * T_ + (size_t)kk * HOP;
            float cmbE[8], cmbO[8];
            #pragma unroll
            for (int j = 0; j < 8; ++j) {
                const float pv = __shfl_up(accO[c * 16 + 8 + j], 1);  // frames[kk-1][8+j]
                cmbE[j] = accE[c * 16 + j] + pv;
                cmbO[j] = accO[c * 16 + j] + accE[c * 16 + 8 + j];    // in-lane
            }
            if (lane == 0) {
                float* hb = ws + (size_t)((m * C_ + c) * NB + bb) * 8;
                *(float4*)&hb[0] = make_float4(accE[c*16+0], accE[c*16+1], accE[c*16+2], accE[c*16+3]);
                *(float4*)&hb[4] = make_float4(accE[c*16+4], accE[c*16+5], accE[c*16+6], accE[c*16+7]);
            } else {
                *(float4*)&ob[0] = make_float4(cmbE[0], cmbE[1], cmbE[2], cmbE[3]);
                *(float4*)&ob[4] = make_float4(cmbE[4], cmbE[5], cmbE[6], cmbE[7]);
            }
            *(float4*)&ob[8]  = make_float4(cmbO[0], cmbO[1], cmbO[2], cmbO[3]);
            *(float4*)&ob[12] = make_float4(cmbO[4], cmbO[5], cmbO[6], cmbO[7]);
            if (lane == 63) {
                float* tb = ws + WS_TAIL_OFF + (size_t)((m * C_ + c) * NB + bb) * 8;
                *(float4*)&tb[0] = make_float4(accO[c*16+8],  accO[c*16+9],  accO[c*16+10], accO[c*16+11]);
                *(float4*)&tb[4] = make_float4(accO[c*16+12], accO[c*16+13], accO[c*16+14], accO[c*16+15]);
            }
        }
    }
}

// out[bb*1024 + j] = head[bb] + tail[bb-1]; global tail = tail[NB-1].
__global__ __launch_bounds__(256)
void boundary_kernel(const float* __restrict__ ws, float* __restrict__ out) {
    const int id = blockIdx.x * 256 + threadIdx.x;
    const int total = M_ * C_ * NB * 8;
    if (id >= total) return;
    const int j  = id & 7;
    const int bb = (id >> 3) % NB;
    const int mc = (id >> 3) / NB;
    float v = ws[(size_t)(mc * NB + bb) * 8 + j];
    if (bb > 0) v += ws[WS_TAIL_OFF + (size_t)(mc * NB + bb - 1) * 8 + j];
    out[(size_t)mc * T_ + (size_t)bb * (BK * HOP) + j] = v;
    if (bb == NB - 1) {
        out[(size_t)mc * T_ + (size_t)K_ * HOP + j] =
            ws[WS_TAIL_OFF + (size_t)(mc * NB + bb) * 8 + j];
    }
}

extern "C" void kernel_launch(void* const* d_in, const int* in_sizes, int n_in,
                              void* d_out, int out_size, void* d_ws, size_t ws_size,
                              hipStream_t stream) {
    const float* mix  = (const float*)d_in[0];
    const float* mask = (const float*)d_in[1];
    const float* Wg   = (const float*)d_in[2];
    float* out = (float*)d_out;
    float* ws  = (float*)d_ws;

    decoder_kernel<<<dim3(M_ * NB), dim3(256), 0, stream>>>(mix, mask, Wg, out, ws);
    boundary_kernel<<<dim3((M_ * C_ * NB * 8 + 255) / 256), dim3(256), 0, stream>>>(ws, out);
}

// Round 4
// 92.630 us; speedup vs baseline: 1.2875x; 1.2875x over previous
//
#include <hip/hip_runtime.h>

// Decoder: frames[m,c,k,l] = sum_n (mix[m,n,k]*mask[m,c,n,k]) * W[l,n]
// then overlap-add (hop=8) into out[m,c,t], T = (K-1)*8+16 = 128008.
// M=4 C=2 N=512 K=16000 L=16.
//
// Block = (m, c, 128 consecutive frames): each lane owns TWO consecutive k's
// (all global loads float2 = 512 B/wave-instr) and ONE c (32 accumulators ->
// VGPR fits 128 -> 16 waves/CU with __launch_bounds__(256,4)). c is the low
// blockIdx bit so the two c-blocks of the same (m,k-range) run concurrently
// and share the mix read through L2/L3. 4 waves each own 128 n's. W staged
// in LDS (wave-uniform broadcast reads). Cross-wave reduce through LDS, then
// wave 0 overlap-adds in-register (odd frame in-lane, even frame via
// shfl_up). Block-boundary head/tail partials -> d_ws; boundary_kernel
// combines them, so every out element is written exactly once with '='.

#define M_   4
#define C_   2
#define N_   512
#define K_   16000
#define L_   16
#define HOP  8
#define T_   ((K_ - 1) * HOP + L_)   // 128008
#define BK   128                     // frames per block (2 per lane)
#define NSEG 4                       // waves per block
#define NPW  (N_ / NSEG)             // 128
#define NB   (K_ / BK)               // 125 k-blocks per m
#define WS_TAIL_OFF (M_ * C_ * NB * 8)

__global__ __launch_bounds__(256, 4)
void decoder_kernel(const float* __restrict__ mix,   // [M][N][K]
                    const float* __restrict__ mask,  // [M][C][N][K]
                    const float* __restrict__ Wg,    // [L][N]
                    float* __restrict__ out,         // [M][C][T]
                    float* __restrict__ ws) {
    __shared__ float lds[8192];      // W [16][512] = 32 KB; reused for reduce

    const int tid  = threadIdx.x;
    const int lane = tid & 63;
    const int w    = tid >> 6;
    const int bidx = blockIdx.x;
    const int c    = bidx & 1;
    const int mk   = bidx >> 1;
    const int m    = mk / NB;
    const int bb   = mk % NB;
    const int k0   = bb * BK;

    for (int i = tid; i < L_ * N_; i += 256) lds[i] = Wg[i];
    __syncthreads();

    float accE[16], accO[16];        // acc[l] for even/odd frame of this lane
    #pragma unroll
    for (int i = 0; i < 16; ++i) { accE[i] = 0.f; accO[i] = 0.f; }

    const int n0w = w * NPW;
    const int kk  = k0 + 2 * lane;   // even frame index of this lane
    const float* pm = mix  + (size_t)m * N_ * K_ + (size_t)n0w * K_ + kk;
    const float* pk = mask + ((size_t)(m * C_ + c) * N_ + n0w) * K_ + kk;

    #pragma unroll 2
    for (int ch = 0; ch < NPW / 4; ++ch) {
        float2 mv[4], av[4];
        #pragma unroll
        for (int j = 0; j < 4; ++j) {
            mv[j] = *(const float2*)&pm[(size_t)j * K_];
            av[j] = *(const float2*)&pk[(size_t)j * K_];
        }
        float sE[4], sO[4];
        #pragma unroll
        for (int j = 0; j < 4; ++j) {
            sE[j] = mv[j].x * av[j].x;
            sO[j] = mv[j].y * av[j].y;
        }
        const int nbase = n0w + ch * 4;
        #pragma unroll
        for (int l = 0; l < L_; ++l) {
            const float4 w4 = *(const float4*)&lds[l * N_ + nbase];
            const float wv[4] = { w4.x, w4.y, w4.z, w4.w };
            #pragma unroll
            for (int j = 0; j < 4; ++j) {
                accE[l] = fmaf(sE[j], wv[j], accE[l]);
                accO[l] = fmaf(sO[j], wv[j], accO[l]);
            }
        }
        pm += (size_t)4 * K_;
        pk += (size_t)4 * K_;
    }

    // ---- cross-wave reduction through LDS (reuses W region; W dead now) ----
    __syncthreads();
    if (w > 0) {
        float* rb = &lds[(w - 1) * 2304 + lane * 36];
        #pragma unroll
        for (int i = 0; i < 4; ++i)
            *(float4*)&rb[i * 4] = make_float4(accE[i*4], accE[i*4+1],
                                               accE[i*4+2], accE[i*4+3]);
        #pragma unroll
        for (int i = 0; i < 4; ++i)
            *(float4*)&rb[16 + i * 4] = make_float4(accO[i*4], accO[i*4+1],
                                                    accO[i*4+2], accO[i*4+3]);
    }
    __syncthreads();

    if (w == 0) {
        #pragma unroll
        for (int r = 0; r < 3; ++r) {
            const float* rb = &lds[r * 2304 + lane * 36];
            #pragma unroll
            for (int i = 0; i < 4; ++i) {
                const float4 v = *(const float4*)&rb[i * 4];
                accE[i*4]   += v.x;  accE[i*4+1] += v.y;
                accE[i*4+2] += v.z;  accE[i*4+3] += v.w;
            }
            #pragma unroll
            for (int i = 0; i < 4; ++i) {
                const float4 v = *(const float4*)&rb[16 + i * 4];
                accO[i*4]   += v.x;  accO[i*4+1] += v.y;
                accO[i*4+2] += v.z;  accO[i*4+3] += v.w;
            }
        }

        // ---- overlap-add: t = k*8+j = frames[k][j] + frames[k-1][8+j] ----
        float* ob = out + (size_t)(m * C_ + c) * T_ + (size_t)kk * HOP;
        float cmbE[8], cmbO[8];
        #pragma unroll
        for (int j = 0; j < 8; ++j) {
            const float pv = __shfl_up(accO[8 + j], 1);   // frames[kk-1][8+j]
            cmbE[j] = accE[j] + pv;
            cmbO[j] = accO[j] + accE[8 + j];              // in-lane
        }
        if (lane == 0) {
            float* hb = ws + (size_t)((m * C_ + c) * NB + bb) * 8;
            *(float4*)&hb[0] = make_float4(accE[0], accE[1], accE[2], accE[3]);
            *(float4*)&hb[4] = make_float4(accE[4], accE[5], accE[6], accE[7]);
        } else {
            *(float4*)&ob[0] = make_float4(cmbE[0], cmbE[1], cmbE[2], cmbE[3]);
            *(float4*)&ob[4] = make_float4(cmbE[4], cmbE[5], cmbE[6], cmbE[7]);
        }
        *(float4*)&ob[8]  = make_float4(cmbO[0], cmbO[1], cmbO[2], cmbO[3]);
        *(float4*)&ob[12] = make_float4(cmbO[4], cmbO[5], cmbO[6], cmbO[7]);
        if (lane == 63) {
            float* tb = ws + WS_TAIL_OFF + (size_t)((m * C_ + c) * NB + bb) * 8;
            *(float4*)&tb[0] = make_float4(accO[8],  accO[9],  accO[10], accO[11]);
            *(float4*)&tb[4] = make_float4(accO[12], accO[13], accO[14], accO[15]);
        }
    }
}

// out[bb*1024 + j] = head[bb] + tail[bb-1]; global tail = tail[NB-1].
__global__ __launch_bounds__(256)
void boundary_kernel(const float* __restrict__ ws, float* __restrict__ out) {
    const int id = blockIdx.x * 256 + threadIdx.x;
    const int total = M_ * C_ * NB * 8;
    if (id >= total) return;
    const int j  = id & 7;
    const int bb = (id >> 3) % NB;
    const int mc = (id >> 3) / NB;
    float v = ws[(size_t)(mc * NB + bb) * 8 + j];
    if (bb > 0) v += ws[WS_TAIL_OFF + (size_t)(mc * NB + bb - 1) * 8 + j];
    out[(size_t)mc * T_ + (size_t)bb * (BK * HOP) + j] = v;
    if (bb == NB - 1) {
        out[(size_t)mc * T_ + (size_t)K_ * HOP + j] =
            ws[WS_TAIL_OFF + (size_t)(mc * NB + bb) * 8 + j];
    }
}

extern "C" void kernel_launch(void* const* d_in, const int* in_sizes, int n_in,
                              void* d_out, int out_size, void* d_ws, size_t ws_size,
                              hipStream_t stream) {
    const float* mix  = (const float*)d_in[0];
    const float* mask = (const float*)d_in[1];
    const float* Wg   = (const float*)d_in[2];
    float* out = (float*)d_out;
    float* ws  = (float*)d_ws;

    decoder_kernel<<<dim3(M_ * NB * C_), dim3(256), 0, stream>>>(mix, mask, Wg, out, ws);
    boundary_kernel<<<dim3((M_ * C_ * NB * 8 + 255) / 256), dim3(256), 0, stream>>>(ws, out);
}

// Round 5
// 87.107 us; speedup vs baseline: 1.3692x; 1.0634x over previous
//
#include <hip/hip_runtime.h>

// Decoder: frames[m,c,k,l] = sum_n (mix[m,n,k]*mask[m,c,n,k]) * W[l,n]
// then overlap-add (hop=8) into out[m,c,t], T = (K-1)*8+16 = 128008.
// M=4 C=2 N=512 K=16000 L=16.
//
// Block = (m, c, 128 consecutive frames): lane owns TWO consecutive k's
// (float2 global loads) and one c (32 accumulators -> VGPR < 128 ->
// 4 blocks/CU, 16 waves/CU). 4 waves each own 128 n's.
// W is read DIRECTLY from global at wave-uniform addresses derived from
// readfirstlane -> compiler emits s_load through the scalar/constant cache
// (W is 32 KB, cache-resident) and FMAs consume the SGPR operand directly.
// This keeps the LDS pipe completely out of the hot loop (r4 spent ~12 cy
// per ds_read_b128 broadcast x 512/wave on it). LDS only holds the small
// cross-wave reduction buffer. Block-boundary head/tail partials -> d_ws;
// boundary_kernel combines them, so every out element is written exactly
// once with '=' -> no memset, no atomics, graph-replay-safe.

#define M_   4
#define C_   2
#define N_   512
#define K_   16000
#define L_   16
#define HOP  8
#define T_   ((K_ - 1) * HOP + L_)   // 128008
#define BK   128                     // frames per block (2 per lane)
#define NSEG 4                       // waves per block
#define NPW  (N_ / NSEG)             // 128
#define NB   (K_ / BK)               // 125 k-blocks per m
#define WS_TAIL_OFF (M_ * C_ * NB * 8)

__global__ __launch_bounds__(256, 4)
void decoder_kernel(const float* __restrict__ mix,   // [M][N][K]
                    const float* __restrict__ mask,  // [M][C][N][K]
                    const float* __restrict__ Wg,    // [L][N]
                    float* __restrict__ out,         // [M][C][T]
                    float* __restrict__ ws) {
    __shared__ float lds[6912];      // reduction buffer: 3 waves x 64 x 36

    const int tid  = threadIdx.x;
    const int lane = tid & 63;
    const int w    = tid >> 6;
    const int bidx = blockIdx.x;
    const int c    = bidx & 1;
    const int mk   = bidx >> 1;
    const int m    = mk / NB;
    const int bb   = mk % NB;
    const int k0   = bb * BK;

    float accE[16], accO[16];        // acc[l] for even/odd frame of this lane
    #pragma unroll
    for (int i = 0; i < 16; ++i) { accE[i] = 0.f; accO[i] = 0.f; }

    const int n0w  = w * NPW;
    // scalarized n-segment base for W addressing -> uniform -> s_load
    const int n0wU = __builtin_amdgcn_readfirstlane(n0w);
    const int kk   = k0 + 2 * lane;  // even frame index of this lane
    const float* pm = mix  + (size_t)m * N_ * K_ + (size_t)n0w * K_ + kk;
    const float* pk = mask + ((size_t)(m * C_ + c) * N_ + n0w) * K_ + kk;

    #pragma unroll 2
    for (int ch = 0; ch < NPW / 4; ++ch) {
        float2 mv[4], av[4];
        #pragma unroll
        for (int j = 0; j < 4; ++j) {
            mv[j] = *(const float2*)&pm[(size_t)j * K_];
            av[j] = *(const float2*)&pk[(size_t)j * K_];
        }
        float sE[4], sO[4];
        #pragma unroll
        for (int j = 0; j < 4; ++j) {
            sE[j] = mv[j].x * av[j].x;
            sO[j] = mv[j].y * av[j].y;
        }
        const int nbase = n0wU + ch * 4;          // scalar
        #pragma unroll
        for (int l = 0; l < L_; ++l) {
            const float4 w4 = *(const float4*)&Wg[l * N_ + nbase];  // s_load
            const float wv[4] = { w4.x, w4.y, w4.z, w4.w };
            #pragma unroll
            for (int j = 0; j < 4; ++j) {
                accE[l] = fmaf(sE[j], wv[j], accE[l]);
                accO[l] = fmaf(sO[j], wv[j], accO[l]);
            }
        }
        pm += (size_t)4 * K_;
        pk += (size_t)4 * K_;
    }

    // ---- cross-wave reduction through LDS ----
    __syncthreads();
    if (w > 0) {
        float* rb = &lds[(w - 1) * 2304 + lane * 36];
        #pragma unroll
        for (int i = 0; i < 4; ++i)
            *(float4*)&rb[i * 4] = make_float4(accE[i*4], accE[i*4+1],
                                               accE[i*4+2], accE[i*4+3]);
        #pragma unroll
        for (int i = 0; i < 4; ++i)
            *(float4*)&rb[16 + i * 4] = make_float4(accO[i*4], accO[i*4+1],
                                                    accO[i*4+2], accO[i*4+3]);
    }
    __syncthreads();

    if (w == 0) {
        #pragma unroll
        for (int r = 0; r < 3; ++r) {
            const float* rb = &lds[r * 2304 + lane * 36];
            #pragma unroll
            for (int i = 0; i < 4; ++i) {
                const float4 v = *(const float4*)&rb[i * 4];
                accE[i*4]   += v.x;  accE[i*4+1] += v.y;
                accE[i*4+2] += v.z;  accE[i*4+3] += v.w;
            }
            #pragma unroll
            for (int i = 0; i < 4; ++i) {
                const float4 v = *(const float4*)&rb[16 + i * 4];
                accO[i*4]   += v.x;  accO[i*4+1] += v.y;
                accO[i*4+2] += v.z;  accO[i*4+3] += v.w;
            }
        }

        // ---- overlap-add: t = k*8+j = frames[k][j] + frames[k-1][8+j] ----
        float* ob = out + (size_t)(m * C_ + c) * T_ + (size_t)kk * HOP;
        float cmbE[8], cmbO[8];
        #pragma unroll
        for (int j = 0; j < 8; ++j) {
            const float pv = __shfl_up(accO[8 + j], 1);   // frames[kk-1][8+j]
            cmbE[j] = accE[j] + pv;
            cmbO[j] = accO[j] + accE[8 + j];              // in-lane
        }
        if (lane == 0) {
            float* hb = ws + (size_t)((m * C_ + c) * NB + bb) * 8;
            *(float4*)&hb[0] = make_float4(accE[0], accE[1], accE[2], accE[3]);
            *(float4*)&hb[4] = make_float4(accE[4], accE[5], accE[6], accE[7]);
        } else {
            *(float4*)&ob[0] = make_float4(cmbE[0], cmbE[1], cmbE[2], cmbE[3]);
            *(float4*)&ob[4] = make_float4(cmbE[4], cmbE[5], cmbE[6], cmbE[7]);
        }
        *(float4*)&ob[8]  = make_float4(cmbO[0], cmbO[1], cmbO[2], cmbO[3]);
        *(float4*)&ob[12] = make_float4(cmbO[4], cmbO[5], cmbO[6], cmbO[7]);
        if (lane == 63) {
            float* tb = ws + WS_TAIL_OFF + (size_t)((m * C_ + c) * NB + bb) * 8;
            *(float4*)&tb[0] = make_float4(accO[8],  accO[9],  accO[10], accO[11]);
            *(float4*)&tb[4] = make_float4(accO[12], accO[13], accO[14], accO[15]);
        }
    }
}

// out[bb*1024 + j] = head[bb] + tail[bb-1]; global tail = tail[NB-1].
__global__ __launch_bounds__(256)
void boundary_kernel(const float* __restrict__ ws, float* __restrict__ out) {
    const int id = blockIdx.x * 256 + threadIdx.x;
    const int total = M_ * C_ * NB * 8;
    if (id >= total) return;
    const int j  = id & 7;
    const int bb = (id >> 3) % NB;
    const int mc = (id >> 3) / NB;
    float v = ws[(size_t)(mc * NB + bb) * 8 + j];
    if (bb > 0) v += ws[WS_TAIL_OFF + (size_t)(mc * NB + bb - 1) * 8 + j];
    out[(size_t)mc * T_ + (size_t)bb * (BK * HOP) + j] = v;
    if (bb == NB - 1) {
        out[(size_t)mc * T_ + (size_t)K_ * HOP + j] =
            ws[WS_TAIL_OFF + (size_t)(mc * NB + bb) * 8 + j];
    }
}

extern "C" void kernel_launch(void* const* d_in, const int* in_sizes, int n_in,
                              void* d_out, int out_size, void* d_ws, size_t ws_size,
                              hipStream_t stream) {
    const float* mix  = (const float*)d_in[0];
    const float* mask = (const float*)d_in[1];
    const float* Wg   = (const float*)d_in[2];
    float* out = (float*)d_out;
    float* ws  = (float*)d_ws;

    decoder_kernel<<<dim3(M_ * NB * C_), dim3(256), 0, stream>>>(mix, mask, Wg, out, ws);
    boundary_kernel<<<dim3((M_ * C_ * NB * 8 + 255) / 256), dim3(256), 0, stream>>>(ws, out);
}

// Round 7
// 84.771 us; speedup vs baseline: 1.4069x; 1.0276x over previous
//
#include <hip/hip_runtime.h>

// Decoder: frames[m,c,k,l] = sum_n (mix[m,n,k]*mask[m,c,n,k]) * W[l,n]
// then overlap-add (hop=8) into out[m,c,t], T = (K-1)*8+16 = 128008.
// M=4 C=2 N=512 K=16000 L=16.
//
// Block = (m, c, 128 consecutive frames): lane owns TWO consecutive k's,
// held as float2 lanes (packed v_pk math). 4 waves each own 128 n's.
// W read via scalar path (uniform address -> s_load, constant-cache).
// Explicit 2-deep register double-buffer on the global loads (A/B sets,
// static indices). Grid = 1008 (63*16): q=bidx>>4, c=bit3, r=bidx&7,
// unit=q*8+r; unit>=500 exits. This is bijective over (unit<500, c) and
// puts the two c-blocks of a unit exactly 8 apart -> same XCD -> the mix
// re-read hits that XCD's L2. (r6 crashed: grid 1000 % 16 != 0 made the
// unguarded remap map bidx 992..999 to units 500..503 -> m=4 -> OOB.)
// Cross-wave reduce through LDS; wave 0 overlap-adds in-register.
// Block-boundary head/tail partials -> d_ws; boundary_kernel combines them:
// every out element written exactly once with '=' (no memset, no atomics).

#define M_   4
#define C_   2
#define N_   512
#define K_   16000
#define L_   16
#define HOP  8
#define T_   ((K_ - 1) * HOP + L_)   // 128008
#define BK   128                     // frames per block (2 per lane)
#define NSEG 4                       // waves per block
#define NPW  (N_ / NSEG)             // 128
#define NCH  (NPW / 4)               // 32 chunks of 4 n's
#define NB   (K_ / BK)               // 125 k-blocks per m
#define NUNITS (M_ * NB)             // 500
#define GRID ((((NUNITS + 7) / 8) * 16))   // 1008
#define WS_TAIL_OFF (M_ * C_ * NB * 8)

typedef float v2f __attribute__((ext_vector_type(2)));

__global__ __launch_bounds__(256, 4)
void decoder_kernel(const float* __restrict__ mix,   // [M][N][K]
                    const float* __restrict__ mask,  // [M][C][N][K]
                    const float* __restrict__ Wg,    // [L][N]
                    float* __restrict__ out,         // [M][C][T]
                    float* __restrict__ ws) {
    __shared__ float lds[6912];      // reduction buffer: 3 waves x 64 x 36

    const int tid  = threadIdx.x;
    const int lane = tid & 63;
    const int w    = tid >> 6;
    const int bidx = blockIdx.x;
    // c-pair 8 apart (same XCD): unit = (bidx>>4)*8 + (bidx&7), c = bit3.
    const int c    = (bidx >> 3) & 1;
    const int unit = ((bidx >> 4) << 3) | (bidx & 7);
    if (unit >= NUNITS) return;      // 8 pad blocks (grid 1008)
    const int m    = unit / NB;
    const int bb   = unit % NB;
    const int k0   = bb * BK;

    v2f acc[16];                     // acc[l] = {even-frame, odd-frame}
    #pragma unroll
    for (int i = 0; i < 16; ++i) acc[i] = (v2f)0.f;

    const int n0w  = w * NPW;
    const int n0wU = __builtin_amdgcn_readfirstlane(n0w);  // uniform -> s_load
    const int kk   = k0 + 2 * lane;
    const float* pm = mix  + (size_t)m * N_ * K_ + (size_t)n0w * K_ + kk;
    const float* pk = mask + ((size_t)(m * C_ + c) * N_ + n0w) * K_ + kk;

    v2f mvA[4], avA[4], mvB[4], avB[4];

#define LOAD(MV, AV)                                          \
    {                                                         \
        _Pragma("unroll")                                     \
        for (int j = 0; j < 4; ++j) {                         \
            MV[j] = *(const v2f*)&pm[(size_t)j * K_];         \
            AV[j] = *(const v2f*)&pk[(size_t)j * K_];         \
        }                                                     \
        pm += (size_t)4 * K_;                                 \
        pk += (size_t)4 * K_;                                 \
    }

#define COMPUTE(MV, AV, CH)                                   \
    {                                                         \
        v2f s[4];                                             \
        _Pragma("unroll")                                     \
        for (int j = 0; j < 4; ++j) s[j] = MV[j] * AV[j];     \
        const int nbase = n0wU + (CH) * 4;                    \
        _Pragma("unroll")                                     \
        for (int l = 0; l < L_; ++l) {                        \
            const float4 w4 = *(const float4*)&Wg[l * N_ + nbase]; \
            acc[l] += s[0] * w4.x;                            \
            acc[l] += s[1] * w4.y;                            \
            acc[l] += s[2] * w4.z;                            \
            acc[l] += s[3] * w4.w;                            \
        }                                                     \
    }

    LOAD(mvA, avA)                       // chunk 0 -> A
    for (int it = 0; it < NCH - 2; it += 2) {
        LOAD(mvB, avB)                   // chunk it+1 in flight
        COMPUTE(mvA, avA, it)
        LOAD(mvA, avA)                   // chunk it+2 in flight
        COMPUTE(mvB, avB, it + 1)
    }
    LOAD(mvB, avB)                       // chunk NCH-1
    COMPUTE(mvA, avA, NCH - 2)
    COMPUTE(mvB, avB, NCH - 1)

#undef LOAD
#undef COMPUTE

    // ---- cross-wave reduction through LDS ----
    __syncthreads();
    if (w > 0) {
        float* rb = &lds[(w - 1) * 2304 + lane * 36];
        #pragma unroll
        for (int i = 0; i < 8; ++i)
            *(float4*)&rb[i * 4] = make_float4(acc[2*i].x, acc[2*i].y,
                                               acc[2*i+1].x, acc[2*i+1].y);
    }
    __syncthreads();

    if (w == 0) {
        #pragma unroll
        for (int r = 0; r < 3; ++r) {
            const float* rb = &lds[r * 2304 + lane * 36];
            #pragma unroll
            for (int i = 0; i < 8; ++i) {
                const float4 v = *(const float4*)&rb[i * 4];
                acc[2*i].x   += v.x;  acc[2*i].y   += v.y;
                acc[2*i+1].x += v.z;  acc[2*i+1].y += v.w;
            }
        }

        // ---- overlap-add: t = k*8+j = frames[k][j] + frames[k-1][8+j] ----
        float* ob = out + (size_t)(m * C_ + c) * T_ + (size_t)kk * HOP;
        float cmbE[8], cmbO[8];
        #pragma unroll
        for (int j = 0; j < 8; ++j) {
            const float pv = __shfl_up(acc[8 + j].y, 1);   // frames[kk-1][8+j]
            cmbE[j] = acc[j].x + pv;
            cmbO[j] = acc[j].y + acc[8 + j].x;             // in-lane
        }
        if (lane == 0) {
            float* hb = ws + (size_t)((m * C_ + c) * NB + bb) * 8;
            *(float4*)&hb[0] = make_float4(acc[0].x, acc[1].x, acc[2].x, acc[3].x);
            *(float4*)&hb[4] = make_float4(acc[4].x, acc[5].x, acc[6].x, acc[7].x);
        } else {
            *(float4*)&ob[0] = make_float4(cmbE[0], cmbE[1], cmbE[2], cmbE[3]);
            *(float4*)&ob[4] = make_float4(cmbE[4], cmbE[5], cmbE[6], cmbE[7]);
        }
        *(float4*)&ob[8]  = make_float4(cmbO[0], cmbO[1], cmbO[2], cmbO[3]);
        *(float4*)&ob[12] = make_float4(cmbO[4], cmbO[5], cmbO[6], cmbO[7]);
        if (lane == 63) {
            float* tb = ws + WS_TAIL_OFF + (size_t)((m * C_ + c) * NB + bb) * 8;
            *(float4*)&tb[0] = make_float4(acc[8].y,  acc[9].y,  acc[10].y, acc[11].y);
            *(float4*)&tb[4] = make_float4(acc[12].y, acc[13].y, acc[14].y, acc[15].y);
        }
    }
}

// out[bb*1024 + j] = head[bb] + tail[bb-1]; global tail = tail[NB-1].
__global__ __launch_bounds__(256)
void boundary_kernel(const float* __restrict__ ws, float* __restrict__ out) {
    const int id = blockIdx.x * 256 + threadIdx.x;
    const int total = M_ * C_ * NB * 8;
    if (id >= total) return;
    const int j  = id & 7;
    const int bb = (id >> 3) % NB;
    const int mc = (id >> 3) / NB;
    float v = ws[(size_t)(mc * NB + bb) * 8 + j];
    if (bb > 0) v += ws[WS_TAIL_OFF + (size_t)(mc * NB + bb - 1) * 8 + j];
    out[(size_t)mc * T_ + (size_t)bb * (BK * HOP) + j] = v;
    if (bb == NB - 1) {
        out[(size_t)mc * T_ + (size_t)K_ * HOP + j] =
            ws[WS_TAIL_OFF + (size_t)(mc * NB + bb) * 8 + j];
    }
}

extern "C" void kernel_launch(void* const* d_in, const int* in_sizes, int n_in,
                              void* d_out, int out_size, void* d_ws, size_t ws_size,
                              hipStream_t stream) {
    const float* mix  = (const float*)d_in[0];
    const float* mask = (const float*)d_in[1];
    const float* Wg   = (const float*)d_in[2];
    float* out = (float*)d_out;
    float* ws  = (float*)d_ws;

    decoder_kernel<<<dim3(GRID), dim3(256), 0, stream>>>(mix, mask, Wg, out, ws);
    boundary_kernel<<<dim3((M_ * C_ * NB * 8 + 255) / 256), dim3(256), 0, stream>>>(ws, out);
}

// Round 8
// 80.562 us; speedup vs baseline: 1.4804x; 1.0522x over previous
//
#include <hip/hip_runtime.h>

// Decoder: frames[m,c,k,l] = sum_n (mix[m,n,k]*mask[m,c,n,k]) * W[l,n]
// then overlap-add (hop=8) into out[m,c,t], T = (K-1)*8+16 = 128008.
// M=4 C=2 N=512 K=16000 L=16.
//
// OCCUPANCY-FIRST variant: one k per lane, acc[16] scalar, dword streaming
// loads -> ~50-60 VGPR, __launch_bounds__(256,8) caps at 64 -> 8 waves/SIMD
// = 32 waves/CU (2x r7). BK=64 frames/block, 4 waves each own 128 n's,
// grid = 2000 = 125*16: c in blockIdx BIT 3 (guard-free bijective since
// 1000 units % 8 == 0) so the two c-blocks of a unit are 8 apart -> same
// XCD -> mix re-read is an L2 hit. W read via scalar path (uniform address
// -> s_load through constant cache; FMA takes SGPR operand directly) -- no
// LDS in the hot loop. LDS only for the 15.4 KB cross-wave reduce
// (stride 20 floats keeps float4 alignment; 8 blocks/CU -> 123 KB < 160).
// Wave 0 overlap-adds in-register via shfl_up; block-boundary head/tail
// partials -> d_ws; boundary_kernel combines them: every out element
// written exactly once with '=' (no memset, no atomics, replay-safe).

#define M_   4
#define C_   2
#define N_   512
#define K_   16000
#define L_   16
#define HOP  8
#define T_   ((K_ - 1) * HOP + L_)   // 128008
#define BK   64                      // frames per block (1 per lane)
#define NSEG 4                       // waves per block
#define NPW  (N_ / NSEG)             // 128
#define NCH  (NPW / 4)               // 32 chunks of 4 n's
#define NB   (K_ / BK)               // 250 k-blocks per m
#define NUNITS (M_ * NB)             // 1000 (divisible by 8 -> no pad)
#define GRID (NUNITS * C_)           // 2000 = 125 * 16
#define RSTRIDE 20                   // reduce-buffer lane stride (floats)
#define WS_TAIL_OFF (M_ * C_ * NB * 8)

__global__ __launch_bounds__(256, 8)
void decoder_kernel(const float* __restrict__ mix,   // [M][N][K]
                    const float* __restrict__ mask,  // [M][C][N][K]
                    const float* __restrict__ Wg,    // [L][N]
                    float* __restrict__ out,         // [M][C][T]
                    float* __restrict__ ws) {
    __shared__ float lds[3 * 64 * RSTRIDE];          // 3840 floats = 15.4 KB

    const int tid  = threadIdx.x;
    const int lane = tid & 63;
    const int w    = tid >> 6;
    const int bidx = blockIdx.x;
    // c-pair 8 apart (same XCD): unit = (bidx>>4)*8 + (bidx&7), c = bit3.
    const int c    = (bidx >> 3) & 1;
    const int unit = ((bidx >> 4) << 3) | (bidx & 7);   // 0..999, bijective
    const int m    = unit / NB;
    const int bb   = unit % NB;
    const int k0   = bb * BK;

    float acc[16];
    #pragma unroll
    for (int i = 0; i < 16; ++i) acc[i] = 0.f;

    const int n0w  = w * NPW;
    const int n0wU = __builtin_amdgcn_readfirstlane(n0w);  // uniform -> s_load
    const int kk   = k0 + lane;
    const float* pm = mix  + (size_t)m * N_ * K_ + (size_t)n0w * K_ + kk;
    const float* pk = mask + ((size_t)(m * C_ + c) * N_ + n0w) * K_ + kk;

    #pragma unroll 2
    for (int ch = 0; ch < NCH; ++ch) {
        float mv[4], av[4];
        #pragma unroll
        for (int j = 0; j < 4; ++j) {
            mv[j] = pm[(size_t)j * K_];
            av[j] = pk[(size_t)j * K_];
        }
        float s[4];
        #pragma unroll
        for (int j = 0; j < 4; ++j) s[j] = mv[j] * av[j];

        const int nbase = n0wU + ch * 4;                   // scalar
        #pragma unroll
        for (int l = 0; l < L_; ++l) {
            const float4 w4 = *(const float4*)&Wg[l * N_ + nbase];  // s_load
            acc[l] = fmaf(s[0], w4.x, acc[l]);
            acc[l] = fmaf(s[1], w4.y, acc[l]);
            acc[l] = fmaf(s[2], w4.z, acc[l]);
            acc[l] = fmaf(s[3], w4.w, acc[l]);
        }
        pm += (size_t)4 * K_;
        pk += (size_t)4 * K_;
    }

    // ---- cross-wave reduction through LDS ----
    __syncthreads();
    if (w > 0) {
        float* rb = &lds[(w - 1) * (64 * RSTRIDE) + lane * RSTRIDE];
        #pragma unroll
        for (int i = 0; i < 4; ++i)
            *(float4*)&rb[i * 4] = make_float4(acc[i*4], acc[i*4+1],
                                               acc[i*4+2], acc[i*4+3]);
    }
    __syncthreads();

    if (w == 0) {
        #pragma unroll
        for (int r = 0; r < 3; ++r) {
            const float* rb = &lds[r * (64 * RSTRIDE) + lane * RSTRIDE];
            #pragma unroll
            for (int i = 0; i < 4; ++i) {
                const float4 v = *(const float4*)&rb[i * 4];
                acc[i*4]   += v.x;  acc[i*4+1] += v.y;
                acc[i*4+2] += v.z;  acc[i*4+3] += v.w;
            }
        }

        // ---- overlap-add: t = k*8+j = frames[k][j] + frames[k-1][8+j] ----
        float* ob = out + (size_t)(m * C_ + c) * T_ + (size_t)kk * HOP;
        float cmb[8];
        #pragma unroll
        for (int j = 0; j < 8; ++j) {
            const float pv = __shfl_up(acc[8 + j], 1);   // frames[kk-1][8+j]
            cmb[j] = acc[j] + pv;
        }
        if (lane == 0) {
            float* hb = ws + (size_t)((m * C_ + c) * NB + bb) * 8;
            *(float4*)&hb[0] = make_float4(acc[0], acc[1], acc[2], acc[3]);
            *(float4*)&hb[4] = make_float4(acc[4], acc[5], acc[6], acc[7]);
        } else {
            *(float4*)&ob[0] = make_float4(cmb[0], cmb[1], cmb[2], cmb[3]);
            *(float4*)&ob[4] = make_float4(cmb[4], cmb[5], cmb[6], cmb[7]);
        }
        if (lane == 63) {
            float* tb = ws + WS_TAIL_OFF + (size_t)((m * C_ + c) * NB + bb) * 8;
            *(float4*)&tb[0] = make_float4(acc[8],  acc[9],  acc[10], acc[11]);
            *(float4*)&tb[4] = make_float4(acc[12], acc[13], acc[14], acc[15]);
        }
    }
}

// out[bb*512 + j] = head[bb] + tail[bb-1]; global tail = tail[NB-1].
__global__ __launch_bounds__(256)
void boundary_kernel(const float* __restrict__ ws, float* __restrict__ out) {
    const int id = blockIdx.x * 256 + threadIdx.x;
    const int total = M_ * C_ * NB * 8;
    if (id >= total) return;
    const int j  = id & 7;
    const int bb = (id >> 3) % NB;
    const int mc = (id >> 3) / NB;
    float v = ws[(size_t)(mc * NB + bb) * 8 + j];
    if (bb > 0) v += ws[WS_TAIL_OFF + (size_t)(mc * NB + bb - 1) * 8 + j];
    out[(size_t)mc * T_ + (size_t)bb * (BK * HOP) + j] = v;
    if (bb == NB - 1) {
        out[(size_t)mc * T_ + (size_t)K_ * HOP + j] =
            ws[WS_TAIL_OFF + (size_t)(mc * NB + bb) * 8 + j];
    }
}

extern "C" void kernel_launch(void* const* d_in, const int* in_sizes, int n_in,
                              void* d_out, int out_size, void* d_ws, size_t ws_size,
                              hipStream_t stream) {
    const float* mix  = (const float*)d_in[0];
    const float* mask = (const float*)d_in[1];
    const float* Wg   = (const float*)d_in[2];
    float* out = (float*)d_out;
    float* ws  = (float*)d_ws;

    decoder_kernel<<<dim3(GRID), dim3(256), 0, stream>>>(mix, mask, Wg, out, ws);
    boundary_kernel<<<dim3((M_ * C_ * NB * 8 + 255) / 256), dim3(256), 0, stream>>>(ws, out);
}